// Round 8
// baseline (472.075 us; speedup 1.0000x reference)
//
#include <hip/hip_runtime.h>
#include <stdint.h>

#define D    128
#define ED   5
#define BLK  512
#define WPB  8
#define W1S  296   // u16 stride, 16B-aligned rows, conflict-free banking
#define W2S  136
#define HS   136
#define US   264
#define GRID 256

typedef __attribute__((ext_vector_type(8))) short bf16x8;
typedef __attribute__((ext_vector_type(4))) float f32x4;

__device__ __forceinline__ unsigned short f2bf(float f) {
    union { float f; uint32_t u; } c; c.f = f;
    uint32_t r = (c.u + 0x7fffu + ((c.u >> 16) & 1u)) >> 16;
    return (unsigned short)r;
}
__device__ __forceinline__ float bflo(uint32_t u) {
    union { uint32_t u; float f; } c; c.u = u << 16; return c.f;
}
__device__ __forceinline__ float bfhi(uint32_t u) {
    union { uint32_t u; float f; } c; c.u = u & 0xffff0000u; return c.f;
}
__device__ __forceinline__ bf16x8 cvt8(const float* __restrict__ p) {
    float4 a = *(const float4*)p;
    float4 b = *(const float4*)(p + 4);
    bf16x8 r;
    r[0] = (short)f2bf(a.x); r[1] = (short)f2bf(a.y);
    r[2] = (short)f2bf(a.z); r[3] = (short)f2bf(a.w);
    r[4] = (short)f2bf(b.x); r[5] = (short)f2bf(b.y);
    r[6] = (short)f2bf(b.z); r[7] = (short)f2bf(b.w);
    return r;
}
__device__ __forceinline__ bool detect64(const int* ei) {
    return (ei[1] == 0) & (ei[3] == 0) & (ei[5] == 0) &
           (ei[7] == 0) & (ei[9] == 0) & (ei[11] == 0);
}

// ---- fused: bf16-convert x  AND  histogram dst counts ----
__global__ __launch_bounds__(512)
void cvt_count_kernel(const float* __restrict__ in, unsigned short* __restrict__ out,
                      int n8, const int* __restrict__ ei, int* __restrict__ cnt, int E) {
    const int i = blockIdx.x * 512 + threadIdx.x;
    if (i < n8) {
        float4 a = ((const float4*)in)[2 * i];
        float4 b = ((const float4*)in)[2 * i + 1];
        union { unsigned short s[8]; uint4 v; } p;
        p.s[0] = f2bf(a.x); p.s[1] = f2bf(a.y); p.s[2] = f2bf(a.z); p.s[3] = f2bf(a.w);
        p.s[4] = f2bf(b.x); p.s[5] = f2bf(b.y); p.s[6] = f2bf(b.z); p.s[7] = f2bf(b.w);
        ((uint4*)out)[i] = p.v;
    } else {
        const int e = i - n8;
        if (e < E) {
            const bool is64 = detect64(ei);
            int d = is64 ? ei[2 * ((size_t)E + e)] : ei[(size_t)E + e];
            atomicAdd(&cnt[d], 1);
        }
    }
}

// ---------------- CSR build (parallel scan) ----------------
__global__ __launch_bounds__(1024)
void scan_blk_kernel(const int* __restrict__ cnt, int* __restrict__ part,
                     int* __restrict__ bsum, int N) {
    __shared__ int wsum[16];
    const int tid = threadIdx.x, wave = tid >> 6, lane = tid & 63;
    const int idx = blockIdx.x * 1024 + tid;
    int v = (idx < N) ? cnt[idx] : 0;
    int s = v;
    #pragma unroll
    for (int off = 1; off < 64; off <<= 1) {
        int t = __shfl_up(s, off, 64);
        if (lane >= off) s += t;
    }
    if (lane == 63) wsum[wave] = s;
    __syncthreads();
    if (wave == 0 && lane < 16) {
        int ws_ = wsum[lane];
        #pragma unroll
        for (int off = 1; off < 16; off <<= 1) {
            int t = __shfl_up(ws_, off, 64);
            if (lane >= off) ws_ += t;
        }
        wsum[lane] = ws_;
    }
    __syncthreads();
    const int excl = ((wave == 0) ? 0 : wsum[wave - 1]) + (s - v);
    if (idx < N) part[idx] = excl;
    if (tid == 0) bsum[blockIdx.x] = wsum[15];
}

__global__ __launch_bounds__(1024)
void scan_top_kernel(int* __restrict__ bsum, int nb) {
    __shared__ int wsum[16];
    const int tid = threadIdx.x, wave = tid >> 6, lane = tid & 63;
    int v = (tid < nb) ? bsum[tid] : 0;
    int s = v;
    #pragma unroll
    for (int off = 1; off < 64; off <<= 1) {
        int t = __shfl_up(s, off, 64);
        if (lane >= off) s += t;
    }
    if (lane == 63) wsum[wave] = s;
    __syncthreads();
    if (wave == 0 && lane < 16) {
        int ws_ = wsum[lane];
        #pragma unroll
        for (int off = 1; off < 16; off <<= 1) {
            int t = __shfl_up(ws_, off, 64);
            if (lane >= off) ws_ += t;
        }
        wsum[lane] = ws_;
    }
    __syncthreads();
    const int excl = ((wave == 0) ? 0 : wsum[wave - 1]) + (s - v);
    if (tid < nb) bsum[tid] = excl;
}

__global__ __launch_bounds__(1024)
void scan_add_kernel(const int* __restrict__ part, const int* __restrict__ bsum,
                     int* __restrict__ starts, int* __restrict__ cursor,
                     int N, int E) {
    const int idx = blockIdx.x * 1024 + threadIdx.x;
    if (idx < N) {
        int v = part[idx] + bsum[blockIdx.x];
        starts[idx] = v;
        cursor[idx] = v;
    }
    if (blockIdx.x == 0 && threadIdx.x == 0) starts[N] = E;
}

// eids[pos] = original edge id at CSR (dst-grouped) position pos
__global__ __launch_bounds__(512)
void fill_kernel(const int* __restrict__ ei, int* __restrict__ cursor,
                 int* __restrict__ eids, int E) {
    const bool is64 = detect64(ei);
    int e = blockIdx.x * 512 + threadIdx.x;
    if (e >= E) return;
    int d = is64 ? ei[2 * ((size_t)E + e)] : ei[(size_t)E + e];
    int pos = atomicAdd(&cursor[d], 1);
    eids[pos] = e;
}

// ---- per-dst sum over CONTIGUOUS CSR-ordered h2 rows (pure streaming) ----
__global__ __launch_bounds__(512)
void agg_kernel(const unsigned short* __restrict__ h2, const int* __restrict__ starts,
                unsigned short* __restrict__ aggb, int N) {
    const int wid = blockIdx.x * WPB + (threadIdx.x >> 6);
    if (wid >= N) return;
    const int lane = threadIdx.x & 63;
    const int s = starts[wid], t = starts[wid + 1];
    const unsigned short* p = h2 + (size_t)s * D + 2 * lane;
    const int n = t - s;
    float a0 = 0.f, a1 = 0.f, b0 = 0.f, b1 = 0.f;
    float p0 = 0.f, p1 = 0.f, q0 = 0.f, q1 = 0.f;
    int j = 0;
    for (; j + 4 <= n; j += 4) {
        uint32_t u0 = *(const uint32_t*)(p + (size_t)(j + 0) * D);
        uint32_t u1 = *(const uint32_t*)(p + (size_t)(j + 1) * D);
        uint32_t u2 = *(const uint32_t*)(p + (size_t)(j + 2) * D);
        uint32_t u3 = *(const uint32_t*)(p + (size_t)(j + 3) * D);
        a0 += bflo(u0); a1 += bfhi(u0);
        b0 += bflo(u1); b1 += bfhi(u1);
        p0 += bflo(u2); p1 += bfhi(u2);
        q0 += bflo(u3); q1 += bfhi(u3);
    }
    for (; j < n; ++j) {
        uint32_t u = *(const uint32_t*)(p + (size_t)j * D);
        a0 += bflo(u); a1 += bfhi(u);
    }
    const float r0 = (a0 + b0) + (p0 + q0);
    const float r1 = (a1 + b1) + (p1 + q1);
    uint32_t o = (uint32_t)f2bf(r0) | ((uint32_t)f2bf(r1) << 16);
    *(uint32_t*)(aggb + (size_t)wid * D + 2 * lane) = o;
}

// One wave = one 16-row m-tile, software-pipelined gathers.
// CSR edge mode: tiles iterate CSR positions p (dst-sorted) -> dst-gather runs
// hit L1/L2, h2 writes contiguous at row p. eids[p] -> original edge id.
template<bool EDGE, bool XBF, bool CSR>
__global__ __launch_bounds__(BLK, 2)
void mlp_kernel(const float* __restrict__ x, const unsigned short* __restrict__ xbf,
                const float* __restrict__ ea, const int* __restrict__ ei,
                const int* __restrict__ eids,
                const float* __restrict__ w1, const float* __restrict__ b1,
                const float* __restrict__ g1, const float* __restrict__ be1,
                const float* __restrict__ w2, const float* __restrict__ b2,
                unsigned short* __restrict__ hout, float* __restrict__ aggf,
                int N, int E)
{
    __shared__ unsigned short w1t[128 * W1S];
    __shared__ unsigned short w2t[128 * W2S];
    __shared__ unsigned short hb[WPB][16 * HS];

    const int tid = threadIdx.x;
    const int KROWS = EDGE ? 288 : 128;
    for (int i = tid; i < KROWS * 128; i += BLK) {
        int k = i >> 7, n = i & 127;
        float v = (!EDGE || k < (2 * D + ED)) ? w1[k * 128 + n] : 0.f;
        w1t[n * W1S + k] = f2bf(v);
    }
    for (int i = tid; i < 128 * 128; i += BLK) {
        int k = i >> 7, n = i & 127;
        w2t[n * W2S + k] = f2bf(w2[k * 128 + n]);
    }
    __syncthreads();

    bool is64 = false;
    if (EDGE) is64 = detect64(ei);

    const int lane = tid & 63, w = tid >> 6;
    const int g = lane >> 4, c = lane & 15;

    float b1v[8], g1v[8], e1v[8], b2v[8];
    #pragma unroll
    for (int nt = 0; nt < 8; ++nt) {
        b1v[nt] = b1[nt * 16 + c];  g1v[nt] = g1[nt * 16 + c];
        e1v[nt] = be1[nt * 16 + c]; b2v[nt] = b2[nt * 16 + c];
    }

    const int cnt = EDGE ? E : N;
    const int nT = (cnt + 15) >> 4;
    const int step = gridDim.x * WPB;
    unsigned short* hw = hb[w];

    // ---- software-pipeline state: indices + A-fragments of the NEXT tile ----
    int pdd = 0, pe = 0;
    size_t paoff = 0, pboff = 0;
    bf16x8 pf[9];

    auto loadIdx = [&](int tl) {
        const int rr = tl * 16 + c;
        const int rc = rr < cnt ? rr : cnt - 1;
        if (EDGE) {
            const int e = CSR ? eids[rc] : rc;   // CSR: position -> edge id
            pe = e;
            int s = is64 ? ei[2 * (size_t)e]       : ei[e];
            pdd   = is64 ? ei[2 * ((size_t)E + e)] : ei[(size_t)E + e];
            paoff = (size_t)s * D;
            pboff = (size_t)pdd * D;
        } else {
            pe = rc;
            paoff = (size_t)rc * D;
        }
    };
    auto loadFrags = [&]() {
        #pragma unroll
        for (int kk = 0; kk < (EDGE ? 8 : 4); ++kk) {
            const size_t o = (kk < 4) ? paoff + kk * 32 : pboff + (kk - 4) * 32;
            if (XBF) pf[kk] = *(const bf16x8*)(xbf + o + 8 * g);
            else     pf[kk] = cvt8(x + o + 8 * g);
        }
        if (EDGE) {
            bf16x8 t;
            #pragma unroll
            for (int j = 0; j < 8; ++j) t[j] = 0;
            if (g == 0) {
                #pragma unroll
                for (int j = 0; j < ED; ++j)
                    t[j] = (short)f2bf(ea[(size_t)pe * ED + j]);
            }
            pf[8] = t;
        }
    };

    int tile = blockIdx.x * WPB + w;
    if (tile < nT) { loadIdx(tile); loadFrags(); }

    for (; tile < nT; tile += step) {
        // consume prefetched state
        bf16x8 af[9];
        #pragma unroll
        for (int kk = 0; kk < (EDGE ? 9 : 4); ++kk) af[kk] = pf[kk];
        const int dd = pdd;
        const int row = tile * 16 + c;

        // issue next tile's index loads (land during GEMM1)
        const int tn = tile + step;
        loadIdx(tn < nT ? tn : tile);

        const f32x4 z = {0.f, 0.f, 0.f, 0.f};
        f32x4 acc[8] = {z, z, z, z, z, z, z, z};
        #pragma unroll
        for (int kk = 0; kk < (EDGE ? 9 : 4); ++kk) {
            const unsigned short* wr = &w1t[c * W1S + kk * 32 + 8 * g];
            #pragma unroll
            for (int nt = 0; nt < 8; ++nt) {
                bf16x8 bf = *(const bf16x8*)(wr + nt * 16 * W1S);
                acc[nt] = __builtin_amdgcn_mfma_f32_16x16x32_bf16(af[kk], bf, acc[nt], 0, 0, 0);
            }
        }

        // issue next tile's gathers (hidden under LN + transpose + GEMM2)
        loadFrags();

        // bias + LN + ReLU; C layout: col = nt*16+c, row = 4g+r
        float mean[4], rstd[4];
        #pragma unroll
        for (int r = 0; r < 4; ++r) {
            float s = 0.f, q = 0.f;
            #pragma unroll
            for (int nt = 0; nt < 8; ++nt) {
                float v = acc[nt][r] + b1v[nt];
                acc[nt][r] = v;
                s += v; q += v * v;
            }
            s += __shfl_xor(s, 1, 64); q += __shfl_xor(q, 1, 64);
            s += __shfl_xor(s, 2, 64); q += __shfl_xor(q, 2, 64);
            s += __shfl_xor(s, 4, 64); q += __shfl_xor(q, 4, 64);
            s += __shfl_xor(s, 8, 64); q += __shfl_xor(q, 8, 64);
            float m = s * (1.f / 128.f);
            float var = q * (1.f / 128.f) - m * m;
            mean[r] = m;
            rstd[r] = rsqrtf(var + 1e-5f);
        }
        #pragma unroll
        for (int nt = 0; nt < 8; ++nt) {
            #pragma unroll
            for (int r = 0; r < 4; ++r) {
                float h = fmaxf((acc[nt][r] - mean[r]) * rstd[r] * g1v[nt] + e1v[nt], 0.f);
                hw[(4 * g + r) * HS + nt * 16 + c] = f2bf(h);
            }
        }
        // wave-private tile: same-wave DS ordering suffices

        f32x4 acc2[8] = {z, z, z, z, z, z, z, z};
        #pragma unroll
        for (int kk = 0; kk < 4; ++kk) {
            bf16x8 hf = *(const bf16x8*)&hw[c * HS + kk * 32 + 8 * g];
            const unsigned short* wr = &w2t[c * W2S + kk * 32 + 8 * g];
            #pragma unroll
            for (int nt = 0; nt < 8; ++nt) {
                bf16x8 bf = *(const bf16x8*)(wr + nt * 16 * W2S);
                acc2[nt] = __builtin_amdgcn_mfma_f32_16x16x32_bf16(hf, bf, acc2[nt], 0, 0, 0);
            }
        }

        if (EDGE && !CSR) {
            int dv[4];
            #pragma unroll
            for (int r = 0; r < 4; ++r) dv[r] = __shfl(dd, 4 * g + r, 64);
            #pragma unroll
            for (int r = 0; r < 4; ++r) {
                const int er = tile * 16 + 4 * g + r;
                if (er < cnt) {
                    float* dst = aggf + (size_t)dv[r] * D + c;
                    #pragma unroll
                    for (int nt = 0; nt < 8; ++nt)
                        atomicAdd(dst + nt * 16, acc2[nt][r] + b2v[nt]);
                }
            }
        } else {
            // bf16 row write via LDS transpose; CSR edge: row p is already the
            // CSR-ordered destination (contiguous stream for agg)
            #pragma unroll
            for (int nt = 0; nt < 8; ++nt) {
                #pragma unroll
                for (int r = 0; r < 4; ++r)
                    hw[(4 * g + r) * HS + nt * 16 + c] = f2bf(acc2[nt][r] + b2v[nt]);
            }
            if (row < cnt) {
                unsigned short* dst = hout + (size_t)row * D;
                #pragma unroll
                for (int j = 0; j < 4; ++j)
                    *(uint4*)(dst + (j * 4 + g) * 8) =
                        *(const uint4*)&hw[c * HS + (j * 4 + g) * 8];
            }
        }
    }
}

// ---- update (MFMA): out = LN(concat(hn,agg)@uw + ub + x) ----
template<bool AGGBF, bool XBF>
__global__ __launch_bounds__(BLK, 4)
void upd2_kernel(const unsigned short* __restrict__ hnb, const void* __restrict__ aggp,
                 const float* __restrict__ x, const unsigned short* __restrict__ xbf,
                 const float* __restrict__ uw, const float* __restrict__ ub,
                 const float* __restrict__ lg, const float* __restrict__ lb,
                 float* __restrict__ out, int N)
{
    __shared__ unsigned short wt[128 * US];
    const int tid = threadIdx.x;
    for (int i = tid; i < 256 * 128; i += BLK) {
        int k = i >> 7, n = i & 127;
        wt[n * US + k] = f2bf(uw[i]);
    }
    __syncthreads();

    const int lane = tid & 63, w = tid >> 6;
    const int g = lane >> 4, c = lane & 15;

    float ubv[8], gv[8], bv[8];
    #pragma unroll
    for (int nt = 0; nt < 8; ++nt) {
        ubv[nt] = ub[nt * 16 + c]; gv[nt] = lg[nt * 16 + c]; bv[nt] = lb[nt * 16 + c];
    }

    const int nT = (N + 15) >> 4;
    for (int tile = blockIdx.x * WPB + w; tile < nT; tile += gridDim.x * WPB) {
        const int row = tile * 16 + c;
        const int rc  = row < N ? row : N - 1;

        const f32x4 z = {0.f, 0.f, 0.f, 0.f};
        f32x4 acc[8] = {z, z, z, z, z, z, z, z};

        #pragma unroll
        for (int kk = 0; kk < 8; ++kk) {
            bf16x8 af;
            if (kk < 4) {
                af = *(const bf16x8*)(hnb + (size_t)rc * D + kk * 32 + 8 * g);
            } else {
                if (AGGBF)
                    af = *(const bf16x8*)((const unsigned short*)aggp +
                                          (size_t)rc * D + (kk - 4) * 32 + 8 * g);
                else
                    af = cvt8((const float*)aggp + (size_t)rc * D + (kk - 4) * 32 + 8 * g);
            }
            const unsigned short* wr = &wt[c * US + kk * 32 + 8 * g];
            #pragma unroll
            for (int nt = 0; nt < 8; ++nt) {
                bf16x8 bf = *(const bf16x8*)(wr + nt * 16 * US);
                acc[nt] = __builtin_amdgcn_mfma_f32_16x16x32_bf16(af, bf, acc[nt], 0, 0, 0);
            }
        }

        float mean[4], rstd[4];
        #pragma unroll
        for (int r = 0; r < 4; ++r) {
            const int row4 = tile * 16 + 4 * g + r;
            const int r4c = row4 < N ? row4 : N - 1;
            float s = 0.f, q = 0.f;
            #pragma unroll
            for (int nt = 0; nt < 8; ++nt) {
                float xr;
                if (XBF) xr = bflo((uint32_t)xbf[(size_t)r4c * D + nt * 16 + c]);
                else     xr = x[(size_t)r4c * D + nt * 16 + c];
                float v = acc[nt][r] + ubv[nt] + xr;
                acc[nt][r] = v;
                s += v; q += v * v;
            }
            s += __shfl_xor(s, 1, 64); q += __shfl_xor(q, 1, 64);
            s += __shfl_xor(s, 2, 64); q += __shfl_xor(q, 2, 64);
            s += __shfl_xor(s, 4, 64); q += __shfl_xor(q, 4, 64);
            s += __shfl_xor(s, 8, 64); q += __shfl_xor(q, 8, 64);
            float m = s * (1.f / 128.f);
            mean[r] = m;
            rstd[r] = rsqrtf(q * (1.f / 128.f) - m * m + 1e-5f);
        }
        #pragma unroll
        for (int r = 0; r < 4; ++r) {
            const int row4 = tile * 16 + 4 * g + r;
            if (row4 < N) {
                #pragma unroll
                for (int nt = 0; nt < 8; ++nt)
                    out[(size_t)row4 * D + nt * 16 + c] =
                        (acc[nt][r] - mean[r]) * rstd[r] * gv[nt] + bv[nt];
            }
        }
    }
}

extern "C" void kernel_launch(void* const* d_in, const int* in_sizes, int n_in,
                              void* d_out, int out_size, void* d_ws, size_t ws_size,
                              hipStream_t stream)
{
    const float* x    = (const float*)d_in[0];
    const float* ea   = (const float*)d_in[1];
    const float* nw1  = (const float*)d_in[3];
    const float* nb1  = (const float*)d_in[4];
    const float* ng1  = (const float*)d_in[5];
    const float* nbe1 = (const float*)d_in[6];
    const float* nw2  = (const float*)d_in[7];
    const float* nb2  = (const float*)d_in[8];
    const float* ew1  = (const float*)d_in[9];
    const float* eb1  = (const float*)d_in[10];
    const float* eg1  = (const float*)d_in[11];
    const float* ebe1 = (const float*)d_in[12];
    const float* ew2  = (const float*)d_in[13];
    const float* eb2  = (const float*)d_in[14];
    const float* uw   = (const float*)d_in[15];
    const float* ub   = (const float*)d_in[16];
    const float* lg   = (const float*)d_in[17];
    const float* lb   = (const float*)d_in[18];
    const int*   eidx = (const int*)d_in[19];

    const int N = in_sizes[0] / D;
    const int E = in_sizes[1] / ED;

    char* base = (char*)d_ws;
    size_t off = 0;
    auto alloc = [&](size_t bytes) -> char* {
        char* p = base + off;
        off = (off + bytes + 255) & ~(size_t)255;
        return p;
    };

    // Tier A layout (CSR-ordered edge processing)
    unsigned short* hnb  = (unsigned short*)alloc((size_t)N * D * 2);
    unsigned short* aggb = (unsigned short*)alloc((size_t)N * D * 2);
    unsigned short* xbf  = (unsigned short*)alloc((size_t)N * D * 2);
    int* cnt    = (int*)alloc((size_t)N * 4);
    int* starts = (int*)alloc(((size_t)N + 1) * 4);
    int* cursor = (int*)alloc((size_t)N * 4);
    int* bsum   = (int*)alloc(1024 * 4);
    int* eids   = (int*)alloc((size_t)E * 4);
    unsigned short* h2 = (unsigned short*)alloc((size_t)E * D * 2);
    const size_t needA = off;

    const int n8 = N * D / 8;
    const int egrid = (E + 511) / 512;
    const int nb = (N + 1023) / 1024;
    const int ugrid = (((N + 15) / 16) + WPB - 1) / WPB;

    if (ws_size >= needA && nb <= 1024) {
        hipMemsetAsync(cnt, 0, (size_t)N * 4, stream);
        cvt_count_kernel<<<(n8 + E + 511) / 512, 512, 0, stream>>>(
            x, xbf, n8, eidx, cnt, E);
        scan_blk_kernel<<<nb, 1024, 0, stream>>>(cnt, cursor, bsum, N);
        scan_top_kernel<<<1, 1024, 0, stream>>>(bsum, nb);
        scan_add_kernel<<<nb, 1024, 0, stream>>>(cursor, bsum, starts, cursor, N, E);
        fill_kernel<<<egrid, 512, 0, stream>>>(eidx, cursor, eids, E);
        mlp_kernel<false, true, true><<<GRID, BLK, 0, stream>>>(
            x, xbf, nullptr, nullptr, nullptr, nw1, nb1, ng1, nbe1, nw2, nb2,
            hnb, nullptr, N, E);
        mlp_kernel<true, true, true><<<GRID, BLK, 0, stream>>>(
            x, xbf, ea, eidx, eids, ew1, eb1, eg1, ebe1, ew2, eb2,
            h2, nullptr, N, E);
        agg_kernel<<<(N + WPB - 1) / WPB, 512, 0, stream>>>(h2, starts, aggb, N);
        upd2_kernel<true, true><<<ugrid, BLK, 0, stream>>>(
            hnb, aggb, x, xbf, uw, ub, lg, lb, (float*)d_out, N);
        return;
    }

    // Tier B layout (atomics, f32 agg)
    off = 0;
    unsigned short* hnb2 = (unsigned short*)alloc((size_t)N * D * 2);
    float* aggf = (float*)alloc((size_t)N * D * 4);
    unsigned short* xbf2 = (unsigned short*)alloc((size_t)N * D * 2);
    const size_t needB = off;

    hipMemsetAsync(aggf, 0, (size_t)N * D * 4, stream);
    if (ws_size >= needB) {
        cvt_count_kernel<<<(n8 + 511) / 512, 512, 0, stream>>>(
            x, xbf2, n8, nullptr, nullptr, 0);
        mlp_kernel<false, true, false><<<GRID, BLK, 0, stream>>>(
            x, xbf2, nullptr, nullptr, nullptr, nw1, nb1, ng1, nbe1, nw2, nb2,
            hnb2, nullptr, N, E);
        mlp_kernel<true, true, false><<<GRID, BLK, 0, stream>>>(
            x, xbf2, ea, eidx, nullptr, ew1, eb1, eg1, ebe1, ew2, eb2,
            nullptr, aggf, N, E);
        upd2_kernel<false, true><<<ugrid, BLK, 0, stream>>>(
            hnb2, aggf, x, xbf2, uw, ub, lg, lb, (float*)d_out, N);
    } else {
        mlp_kernel<false, false, false><<<GRID, BLK, 0, stream>>>(
            x, nullptr, nullptr, nullptr, nullptr, nw1, nb1, ng1, nbe1, nw2, nb2,
            hnb2, nullptr, N, E);
        mlp_kernel<true, false, false><<<GRID, BLK, 0, stream>>>(
            x, nullptr, ea, eidx, nullptr, ew1, eb1, eg1, ebe1, ew2, eb2,
            nullptr, aggf, N, E);
        upd2_kernel<false, false><<<ugrid, BLK, 0, stream>>>(
            hnb2, aggf, x, nullptr, uw, ub, lg, lb, (float*)d_out, N);
    }
}

// Round 9
// 410.036 us; speedup vs baseline: 1.1513x; 1.1513x over previous
//
#include <hip/hip_runtime.h>
#include <stdint.h>

#define D    128
#define ED   5
#define BLK  512
#define WPB  8
#define W1S  296   // u16 stride, 16B-aligned rows, conflict-free banking
#define W2S  136
#define HS   136
#define US   264
#define GRID 256

typedef __attribute__((ext_vector_type(8))) short bf16x8;
typedef __attribute__((ext_vector_type(4))) float f32x4;

__device__ __forceinline__ unsigned short f2bf(float f) {
    union { float f; uint32_t u; } c; c.f = f;
    uint32_t r = (c.u + 0x7fffu + ((c.u >> 16) & 1u)) >> 16;
    return (unsigned short)r;
}
__device__ __forceinline__ float bflo(uint32_t u) {
    union { uint32_t u; float f; } c; c.u = u << 16; return c.f;
}
__device__ __forceinline__ float bfhi(uint32_t u) {
    union { uint32_t u; float f; } c; c.u = u & 0xffff0000u; return c.f;
}
__device__ __forceinline__ bf16x8 cvt8(const float* __restrict__ p) {
    float4 a = *(const float4*)p;
    float4 b = *(const float4*)(p + 4);
    bf16x8 r;
    r[0] = (short)f2bf(a.x); r[1] = (short)f2bf(a.y);
    r[2] = (short)f2bf(a.z); r[3] = (short)f2bf(a.w);
    r[4] = (short)f2bf(b.x); r[5] = (short)f2bf(b.y);
    r[6] = (short)f2bf(b.z); r[7] = (short)f2bf(b.w);
    return r;
}
__device__ __forceinline__ bool detect64(const int* ei) {
    return (ei[1] == 0) & (ei[3] == 0) & (ei[5] == 0) &
           (ei[7] == 0) & (ei[9] == 0) & (ei[11] == 0);
}

// ---- fused: bf16-convert x AND histogram dst counts ----
__global__ __launch_bounds__(512)
void cvt_count_kernel(const float* __restrict__ in, unsigned short* __restrict__ out,
                      int n8, const int* __restrict__ ei, int* __restrict__ cnt, int E) {
    const int i = blockIdx.x * 512 + threadIdx.x;
    if (i < n8) {
        float4 a = ((const float4*)in)[2 * i];
        float4 b = ((const float4*)in)[2 * i + 1];
        union { unsigned short s[8]; uint4 v; } p;
        p.s[0] = f2bf(a.x); p.s[1] = f2bf(a.y); p.s[2] = f2bf(a.z); p.s[3] = f2bf(a.w);
        p.s[4] = f2bf(b.x); p.s[5] = f2bf(b.y); p.s[6] = f2bf(b.z); p.s[7] = f2bf(b.w);
        ((uint4*)out)[i] = p.v;
    } else {
        const int e = i - n8;
        if (e < E) {
            const bool is64 = detect64(ei);
            int d = is64 ? ei[2 * ((size_t)E + e)] : ei[(size_t)E + e];
            atomicAdd(&cnt[d], 1);
        }
    }
}

// ---------------- CSR build (parallel scan) ----------------
__global__ __launch_bounds__(1024)
void scan_blk_kernel(const int* __restrict__ cnt, int* __restrict__ part,
                     int* __restrict__ bsum, int N) {
    __shared__ int wsum[16];
    const int tid = threadIdx.x, wave = tid >> 6, lane = tid & 63;
    const int idx = blockIdx.x * 1024 + tid;
    int v = (idx < N) ? cnt[idx] : 0;
    int s = v;
    #pragma unroll
    for (int off = 1; off < 64; off <<= 1) {
        int t = __shfl_up(s, off, 64);
        if (lane >= off) s += t;
    }
    if (lane == 63) wsum[wave] = s;
    __syncthreads();
    if (wave == 0 && lane < 16) {
        int ws_ = wsum[lane];
        #pragma unroll
        for (int off = 1; off < 16; off <<= 1) {
            int t = __shfl_up(ws_, off, 64);
            if (lane >= off) ws_ += t;
        }
        wsum[lane] = ws_;
    }
    __syncthreads();
    const int excl = ((wave == 0) ? 0 : wsum[wave - 1]) + (s - v);
    if (idx < N) part[idx] = excl;
    if (tid == 0) bsum[blockIdx.x] = wsum[15];
}

__global__ __launch_bounds__(1024)
void scan_top_kernel(int* __restrict__ bsum, int nb) {
    __shared__ int wsum[16];
    const int tid = threadIdx.x, wave = tid >> 6, lane = tid & 63;
    int v = (tid < nb) ? bsum[tid] : 0;
    int s = v;
    #pragma unroll
    for (int off = 1; off < 64; off <<= 1) {
        int t = __shfl_up(s, off, 64);
        if (lane >= off) s += t;
    }
    if (lane == 63) wsum[wave] = s;
    __syncthreads();
    if (wave == 0 && lane < 16) {
        int ws_ = wsum[lane];
        #pragma unroll
        for (int off = 1; off < 16; off <<= 1) {
            int t = __shfl_up(ws_, off, 64);
            if (lane >= off) ws_ += t;
        }
        wsum[lane] = ws_;
    }
    __syncthreads();
    const int excl = ((wave == 0) ? 0 : wsum[wave - 1]) + (s - v);
    if (tid < nb) bsum[tid] = excl;
}

__global__ __launch_bounds__(1024)
void scan_add_kernel(const int* __restrict__ part, const int* __restrict__ bsum,
                     int* __restrict__ starts, int* __restrict__ cursor,
                     int N, int E) {
    const int idx = blockIdx.x * 1024 + threadIdx.x;
    if (idx < N) {
        int v = part[idx] + bsum[blockIdx.x];
        starts[idx] = v;
        cursor[idx] = v;
    }
    if (blockIdx.x == 0 && threadIdx.x == 0) starts[N] = E;
}

// slot[e] = CSR (dst-grouped) position of edge e; coalesced write by e
__global__ __launch_bounds__(512)
void fill_kernel(const int* __restrict__ ei, int* __restrict__ cursor,
                 int* __restrict__ slotp, int E) {
    const bool is64 = detect64(ei);
    int e = blockIdx.x * 512 + threadIdx.x;
    if (e >= E) return;
    int d = is64 ? ei[2 * ((size_t)E + e)] : ei[(size_t)E + e];
    slotp[e] = atomicAdd(&cursor[d], 1);
}

// One wave = one 16-row m-tile, software-pipelined gathers.
// Edges processed in ORIGINAL order (ea + slot reads coalesced);
// h2 rows scattered to CSR positions (fire-and-forget writes).
template<bool EDGE, bool XBF, bool CSR>
__global__ __launch_bounds__(BLK, 2)
void mlp_kernel(const float* __restrict__ x, const unsigned short* __restrict__ xbf,
                const float* __restrict__ ea, const int* __restrict__ ei,
                const int* __restrict__ slotp,
                const float* __restrict__ w1, const float* __restrict__ b1,
                const float* __restrict__ g1, const float* __restrict__ be1,
                const float* __restrict__ w2, const float* __restrict__ b2,
                unsigned short* __restrict__ hout, float* __restrict__ aggf,
                int N, int E)
{
    __shared__ unsigned short w1t[128 * W1S];
    __shared__ unsigned short w2t[128 * W2S];
    __shared__ unsigned short hb[WPB][16 * HS];

    const int tid = threadIdx.x;
    const int KROWS = EDGE ? 288 : 128;
    for (int i = tid; i < KROWS * 128; i += BLK) {
        int k = i >> 7, n = i & 127;
        float v = (!EDGE || k < (2 * D + ED)) ? w1[k * 128 + n] : 0.f;
        w1t[n * W1S + k] = f2bf(v);
    }
    for (int i = tid; i < 128 * 128; i += BLK) {
        int k = i >> 7, n = i & 127;
        w2t[n * W2S + k] = f2bf(w2[k * 128 + n]);
    }
    __syncthreads();

    bool is64 = false;
    if (EDGE) is64 = detect64(ei);

    const int lane = tid & 63, w = tid >> 6;
    const int g = lane >> 4, c = lane & 15;

    float b1v[8], g1v[8], e1v[8], b2v[8];
    #pragma unroll
    for (int nt = 0; nt < 8; ++nt) {
        b1v[nt] = b1[nt * 16 + c];  g1v[nt] = g1[nt * 16 + c];
        e1v[nt] = be1[nt * 16 + c]; b2v[nt] = b2[nt * 16 + c];
    }

    const int cnt = EDGE ? E : N;
    const int nT = (cnt + 15) >> 4;
    const int step = gridDim.x * WPB;
    unsigned short* hw = hb[w];

    // ---- software-pipeline state: indices + A-fragments of the NEXT tile ----
    int pdd = 0, prc = 0, psl = 0;
    size_t paoff = 0, pboff = 0;
    bf16x8 pf[9];

    auto loadIdx = [&](int tl) {
        const int rr = tl * 16 + c;
        const int rc = rr < cnt ? rr : cnt - 1;
        prc = rc;
        if (EDGE) {
            int s = is64 ? ei[2 * (size_t)rc]       : ei[rc];
            pdd   = is64 ? ei[2 * ((size_t)E + rc)] : ei[(size_t)E + rc];
            paoff = (size_t)s * D;
            pboff = (size_t)pdd * D;
            if (CSR) psl = slotp[rc];
        } else {
            paoff = (size_t)rc * D;
        }
    };
    auto loadFrags = [&]() {
        #pragma unroll
        for (int kk = 0; kk < (EDGE ? 8 : 4); ++kk) {
            const size_t o = (kk < 4) ? paoff + kk * 32 : pboff + (kk - 4) * 32;
            if (XBF) pf[kk] = *(const bf16x8*)(xbf + o + 8 * g);
            else     pf[kk] = cvt8(x + o + 8 * g);
        }
        if (EDGE) {
            bf16x8 t;
            #pragma unroll
            for (int j = 0; j < 8; ++j) t[j] = 0;
            if (g == 0) {
                #pragma unroll
                for (int j = 0; j < ED; ++j)
                    t[j] = (short)f2bf(ea[(size_t)prc * ED + j]);
            }
            pf[8] = t;
        }
    };

    int tile = blockIdx.x * WPB + w;
    if (tile < nT) { loadIdx(tile); loadFrags(); }

    for (; tile < nT; tile += step) {
        // consume prefetched state
        bf16x8 af[9];
        #pragma unroll
        for (int kk = 0; kk < (EDGE ? 9 : 4); ++kk) af[kk] = pf[kk];
        const int dd = pdd;
        const int sl = psl;
        const int row = tile * 16 + c;

        // issue next tile's index loads (land during GEMM1)
        const int tn = tile + step;
        loadIdx(tn < nT ? tn : tile);

        const f32x4 z = {0.f, 0.f, 0.f, 0.f};
        f32x4 acc[8] = {z, z, z, z, z, z, z, z};
        #pragma unroll
        for (int kk = 0; kk < (EDGE ? 9 : 4); ++kk) {
            const unsigned short* wr = &w1t[c * W1S + kk * 32 + 8 * g];
            #pragma unroll
            for (int nt = 0; nt < 8; ++nt) {
                bf16x8 bf = *(const bf16x8*)(wr + nt * 16 * W1S);
                acc[nt] = __builtin_amdgcn_mfma_f32_16x16x32_bf16(af[kk], bf, acc[nt], 0, 0, 0);
            }
        }

        // issue next tile's gathers (hidden under LN + transpose + GEMM2)
        loadFrags();

        // bias + LN + ReLU; C layout: col = nt*16+c, row = 4g+r
        float mean[4], rstd[4];
        #pragma unroll
        for (int r = 0; r < 4; ++r) {
            float s = 0.f, q = 0.f;
            #pragma unroll
            for (int nt = 0; nt < 8; ++nt) {
                float v = acc[nt][r] + b1v[nt];
                acc[nt][r] = v;
                s += v; q += v * v;
            }
            s += __shfl_xor(s, 1, 64); q += __shfl_xor(q, 1, 64);
            s += __shfl_xor(s, 2, 64); q += __shfl_xor(q, 2, 64);
            s += __shfl_xor(s, 4, 64); q += __shfl_xor(q, 4, 64);
            s += __shfl_xor(s, 8, 64); q += __shfl_xor(q, 8, 64);
            float m = s * (1.f / 128.f);
            float var = q * (1.f / 128.f) - m * m;
            mean[r] = m;
            rstd[r] = rsqrtf(var + 1e-5f);
        }
        #pragma unroll
        for (int nt = 0; nt < 8; ++nt) {
            #pragma unroll
            for (int r = 0; r < 4; ++r) {
                float h = fmaxf((acc[nt][r] - mean[r]) * rstd[r] * g1v[nt] + e1v[nt], 0.f);
                hw[(4 * g + r) * HS + nt * 16 + c] = f2bf(h);
            }
        }
        // wave-private tile: same-wave DS ordering suffices

        f32x4 acc2[8] = {z, z, z, z, z, z, z, z};
        #pragma unroll
        for (int kk = 0; kk < 4; ++kk) {
            bf16x8 hf = *(const bf16x8*)&hw[c * HS + kk * 32 + 8 * g];
            const unsigned short* wr = &w2t[c * W2S + kk * 32 + 8 * g];
            #pragma unroll
            for (int nt = 0; nt < 8; ++nt) {
                bf16x8 bf = *(const bf16x8*)(wr + nt * 16 * W2S);
                acc2[nt] = __builtin_amdgcn_mfma_f32_16x16x32_bf16(hf, bf, acc2[nt], 0, 0, 0);
            }
        }

        if (EDGE && !CSR) {
            int dv[4];
            #pragma unroll
            for (int r = 0; r < 4; ++r) dv[r] = __shfl(dd, 4 * g + r, 64);
            #pragma unroll
            for (int r = 0; r < 4; ++r) {
                const int er = tile * 16 + 4 * g + r;
                if (er < cnt) {
                    float* dst = aggf + (size_t)dv[r] * D + c;
                    #pragma unroll
                    for (int nt = 0; nt < 8; ++nt)
                        atomicAdd(dst + nt * 16, acc2[nt][r] + b2v[nt]);
                }
            }
        } else {
            // bf16 row write via LDS transpose; edge CSR: scatter to CSR slot
            #pragma unroll
            for (int nt = 0; nt < 8; ++nt) {
                #pragma unroll
                for (int r = 0; r < 4; ++r)
                    hw[(4 * g + r) * HS + nt * 16 + c] = f2bf(acc2[nt][r] + b2v[nt]);
            }
            if (row < cnt) {
                const int orow = (EDGE && CSR) ? sl : row;
                unsigned short* dst = hout + (size_t)orow * D;
                #pragma unroll
                for (int j = 0; j < 4; ++j)
                    *(uint4*)(dst + (j * 4 + g) * 8) =
                        *(const uint4*)&hw[c * HS + (j * 4 + g) * 8];
            }
        }
    }
}

// ---- fused aggregate + update (MFMA):
//      agg[n] = sum of CSR-contiguous h2 rows; out = LN(concat(hn,agg)@uw+ub+x)
template<bool XBF>
__global__ __launch_bounds__(BLK, 2)
void upd3_kernel(const unsigned short* __restrict__ hnb,
                 const unsigned short* __restrict__ h2, const int* __restrict__ starts,
                 const float* __restrict__ x, const unsigned short* __restrict__ xbf,
                 const float* __restrict__ uw, const float* __restrict__ ub,
                 const float* __restrict__ lg, const float* __restrict__ lb,
                 float* __restrict__ out, int N)
{
    __shared__ unsigned short wt[128 * US];
    const int tid = threadIdx.x;
    for (int i = tid; i < 256 * 128; i += BLK) {
        int k = i >> 7, n = i & 127;
        wt[n * US + k] = f2bf(uw[i]);
    }
    __syncthreads();

    const int lane = tid & 63, w = tid >> 6;
    const int g = lane >> 4, c = lane & 15;

    float ubv[8], gv[8], bv[8];
    #pragma unroll
    for (int nt = 0; nt < 8; ++nt) {
        ubv[nt] = ub[nt * 16 + c]; gv[nt] = lg[nt * 16 + c]; bv[nt] = lb[nt * 16 + c];
    }

    const int nT = (N + 15) >> 4;
    for (int tile = blockIdx.x * WPB + w; tile < nT; tile += gridDim.x * WPB) {
        const int row = tile * 16 + c;
        const int rc  = row < N ? row : N - 1;

        // ---- in-register aggregation over this node's CSR-contiguous h2 rows
        // lane (c,g) owns 4 slices of 8 bf16: cols kk*32 + 8g .. +8
        const int s = starts[rc], t = starts[rc + 1];
        float ag0[8] = {0,0,0,0,0,0,0,0}, ag1[8] = {0,0,0,0,0,0,0,0};
        float ag2[8] = {0,0,0,0,0,0,0,0}, ag3[8] = {0,0,0,0,0,0,0,0};
        for (int j = s; j < t; ++j) {
            const unsigned short* pr = h2 + (size_t)j * D + 8 * g;
            uint4 v0 = *(const uint4*)(pr);
            uint4 v1 = *(const uint4*)(pr + 32);
            uint4 v2 = *(const uint4*)(pr + 64);
            uint4 v3 = *(const uint4*)(pr + 96);
            ag0[0] += bflo(v0.x); ag0[1] += bfhi(v0.x); ag0[2] += bflo(v0.y); ag0[3] += bfhi(v0.y);
            ag0[4] += bflo(v0.z); ag0[5] += bfhi(v0.z); ag0[6] += bflo(v0.w); ag0[7] += bfhi(v0.w);
            ag1[0] += bflo(v1.x); ag1[1] += bfhi(v1.x); ag1[2] += bflo(v1.y); ag1[3] += bfhi(v1.y);
            ag1[4] += bflo(v1.z); ag1[5] += bfhi(v1.z); ag1[6] += bflo(v1.w); ag1[7] += bfhi(v1.w);
            ag2[0] += bflo(v2.x); ag2[1] += bfhi(v2.x); ag2[2] += bflo(v2.y); ag2[3] += bfhi(v2.y);
            ag2[4] += bflo(v2.z); ag2[5] += bfhi(v2.z); ag2[6] += bflo(v2.w); ag2[7] += bfhi(v2.w);
            ag3[0] += bflo(v3.x); ag3[1] += bfhi(v3.x); ag3[2] += bflo(v3.y); ag3[3] += bfhi(v3.y);
            ag3[4] += bflo(v3.z); ag3[5] += bfhi(v3.z); ag3[6] += bflo(v3.w); ag3[7] += bfhi(v3.w);
        }

        const f32x4 z = {0.f, 0.f, 0.f, 0.f};
        f32x4 acc[8] = {z, z, z, z, z, z, z, z};

        #pragma unroll
        for (int kk = 0; kk < 8; ++kk) {
            bf16x8 af;
            if (kk < 4) {
                af = *(const bf16x8*)(hnb + (size_t)rc * D + kk * 32 + 8 * g);
            } else {
                const float* agp = (kk == 4) ? ag0 : (kk == 5) ? ag1 : (kk == 6) ? ag2 : ag3;
                #pragma unroll
                for (int i = 0; i < 8; ++i) af[i] = (short)f2bf(agp[i]);
            }
            const unsigned short* wr = &wt[c * US + kk * 32 + 8 * g];
            #pragma unroll
            for (int nt = 0; nt < 8; ++nt) {
                bf16x8 bf = *(const bf16x8*)(wr + nt * 16 * US);
                acc[nt] = __builtin_amdgcn_mfma_f32_16x16x32_bf16(af, bf, acc[nt], 0, 0, 0);
            }
        }

        float mean[4], rstd[4];
        #pragma unroll
        for (int r = 0; r < 4; ++r) {
            const int row4 = tile * 16 + 4 * g + r;
            const int r4c = row4 < N ? row4 : N - 1;
            float s2 = 0.f, q = 0.f;
            #pragma unroll
            for (int nt = 0; nt < 8; ++nt) {
                float xr;
                if (XBF) xr = bflo((uint32_t)xbf[(size_t)r4c * D + nt * 16 + c]);
                else     xr = x[(size_t)r4c * D + nt * 16 + c];
                float v = acc[nt][r] + ubv[nt] + xr;
                acc[nt][r] = v;
                s2 += v; q += v * v;
            }
            s2 += __shfl_xor(s2, 1, 64); q += __shfl_xor(q, 1, 64);
            s2 += __shfl_xor(s2, 2, 64); q += __shfl_xor(q, 2, 64);
            s2 += __shfl_xor(s2, 4, 64); q += __shfl_xor(q, 4, 64);
            s2 += __shfl_xor(s2, 8, 64); q += __shfl_xor(q, 8, 64);
            float m = s2 * (1.f / 128.f);
            mean[r] = m;
            rstd[r] = rsqrtf(q * (1.f / 128.f) - m * m + 1e-5f);
        }
        #pragma unroll
        for (int r = 0; r < 4; ++r) {
            const int row4 = tile * 16 + 4 * g + r;
            if (row4 < N) {
                #pragma unroll
                for (int nt = 0; nt < 8; ++nt)
                    out[(size_t)row4 * D + nt * 16 + c] =
                        (acc[nt][r] - mean[r]) * rstd[r] * gv[nt] + bv[nt];
            }
        }
    }
}

// ---- tier-B update (separate agg buffer) ----
template<bool AGGBF, bool XBF>
__global__ __launch_bounds__(BLK, 4)
void upd2_kernel(const unsigned short* __restrict__ hnb, const void* __restrict__ aggp,
                 const float* __restrict__ x, const unsigned short* __restrict__ xbf,
                 const float* __restrict__ uw, const float* __restrict__ ub,
                 const float* __restrict__ lg, const float* __restrict__ lb,
                 float* __restrict__ out, int N)
{
    __shared__ unsigned short wt[128 * US];
    const int tid = threadIdx.x;
    for (int i = tid; i < 256 * 128; i += BLK) {
        int k = i >> 7, n = i & 127;
        wt[n * US + k] = f2bf(uw[i]);
    }
    __syncthreads();

    const int lane = tid & 63, w = tid >> 6;
    const int g = lane >> 4, c = lane & 15;

    float ubv[8], gv[8], bv[8];
    #pragma unroll
    for (int nt = 0; nt < 8; ++nt) {
        ubv[nt] = ub[nt * 16 + c]; gv[nt] = lg[nt * 16 + c]; bv[nt] = lb[nt * 16 + c];
    }

    const int nT = (N + 15) >> 4;
    for (int tile = blockIdx.x * WPB + w; tile < nT; tile += gridDim.x * WPB) {
        const int row = tile * 16 + c;
        const int rc  = row < N ? row : N - 1;

        const f32x4 z = {0.f, 0.f, 0.f, 0.f};
        f32x4 acc[8] = {z, z, z, z, z, z, z, z};

        #pragma unroll
        for (int kk = 0; kk < 8; ++kk) {
            bf16x8 af;
            if (kk < 4) {
                af = *(const bf16x8*)(hnb + (size_t)rc * D + kk * 32 + 8 * g);
            } else {
                if (AGGBF)
                    af = *(const bf16x8*)((const unsigned short*)aggp +
                                          (size_t)rc * D + (kk - 4) * 32 + 8 * g);
                else
                    af = cvt8((const float*)aggp + (size_t)rc * D + (kk - 4) * 32 + 8 * g);
            }
            const unsigned short* wr = &wt[c * US + kk * 32 + 8 * g];
            #pragma unroll
            for (int nt = 0; nt < 8; ++nt) {
                bf16x8 bf = *(const bf16x8*)(wr + nt * 16 * US);
                acc[nt] = __builtin_amdgcn_mfma_f32_16x16x32_bf16(af, bf, acc[nt], 0, 0, 0);
            }
        }

        float mean[4], rstd[4];
        #pragma unroll
        for (int r = 0; r < 4; ++r) {
            const int row4 = tile * 16 + 4 * g + r;
            const int r4c = row4 < N ? row4 : N - 1;
            float s = 0.f, q = 0.f;
            #pragma unroll
            for (int nt = 0; nt < 8; ++nt) {
                float xr;
                if (XBF) xr = bflo((uint32_t)xbf[(size_t)r4c * D + nt * 16 + c]);
                else     xr = x[(size_t)r4c * D + nt * 16 + c];
                float v = acc[nt][r] + ubv[nt] + xr;
                acc[nt][r] = v;
                s += v; q += v * v;
            }
            s += __shfl_xor(s, 1, 64); q += __shfl_xor(q, 1, 64);
            s += __shfl_xor(s, 2, 64); q += __shfl_xor(q, 2, 64);
            s += __shfl_xor(s, 4, 64); q += __shfl_xor(q, 4, 64);
            s += __shfl_xor(s, 8, 64); q += __shfl_xor(q, 8, 64);
            float m = s * (1.f / 128.f);
            mean[r] = m;
            rstd[r] = rsqrtf(q * (1.f / 128.f) - m * m + 1e-5f);
        }
        #pragma unroll
        for (int r = 0; r < 4; ++r) {
            const int row4 = tile * 16 + 4 * g + r;
            if (row4 < N) {
                #pragma unroll
                for (int nt = 0; nt < 8; ++nt)
                    out[(size_t)row4 * D + nt * 16 + c] =
                        (acc[nt][r] - mean[r]) * rstd[r] * gv[nt] + bv[nt];
            }
        }
    }
}

extern "C" void kernel_launch(void* const* d_in, const int* in_sizes, int n_in,
                              void* d_out, int out_size, void* d_ws, size_t ws_size,
                              hipStream_t stream)
{
    const float* x    = (const float*)d_in[0];
    const float* ea   = (const float*)d_in[1];
    const float* nw1  = (const float*)d_in[3];
    const float* nb1  = (const float*)d_in[4];
    const float* ng1  = (const float*)d_in[5];
    const float* nbe1 = (const float*)d_in[6];
    const float* nw2  = (const float*)d_in[7];
    const float* nb2  = (const float*)d_in[8];
    const float* ew1  = (const float*)d_in[9];
    const float* eb1  = (const float*)d_in[10];
    const float* eg1  = (const float*)d_in[11];
    const float* ebe1 = (const float*)d_in[12];
    const float* ew2  = (const float*)d_in[13];
    const float* eb2  = (const float*)d_in[14];
    const float* uw   = (const float*)d_in[15];
    const float* ub   = (const float*)d_in[16];
    const float* lg   = (const float*)d_in[17];
    const float* lb   = (const float*)d_in[18];
    const int*   eidx = (const int*)d_in[19];

    const int N = in_sizes[0] / D;
    const int E = in_sizes[1] / ED;

    char* base = (char*)d_ws;
    size_t off = 0;
    auto alloc = [&](size_t bytes) -> char* {
        char* p = base + off;
        off = (off + bytes + 255) & ~(size_t)255;
        return p;
    };

    // Tier A layout (CSR slot-scatter + fused agg/update)
    unsigned short* hnb  = (unsigned short*)alloc((size_t)N * D * 2);
    unsigned short* xbf  = (unsigned short*)alloc((size_t)N * D * 2);
    int* cnt    = (int*)alloc((size_t)N * 4);
    int* starts = (int*)alloc(((size_t)N + 1) * 4);
    int* cursor = (int*)alloc((size_t)N * 4);
    int* bsum   = (int*)alloc(1024 * 4);
    int* slotA  = (int*)alloc((size_t)E * 4);
    unsigned short* h2 = (unsigned short*)alloc((size_t)E * D * 2);
    const size_t needA = off;

    const int n8 = N * D / 8;
    const int egrid = (E + 511) / 512;
    const int nb = (N + 1023) / 1024;
    const int ugrid = (((N + 15) / 16) + WPB - 1) / WPB;

    if (ws_size >= needA && nb <= 1024) {
        hipMemsetAsync(cnt, 0, (size_t)N * 4, stream);
        cvt_count_kernel<<<(n8 + E + 511) / 512, 512, 0, stream>>>(
            x, xbf, n8, eidx, cnt, E);
        scan_blk_kernel<<<nb, 1024, 0, stream>>>(cnt, cursor, bsum, N);
        scan_top_kernel<<<1, 1024, 0, stream>>>(bsum, nb);
        scan_add_kernel<<<nb, 1024, 0, stream>>>(cursor, bsum, starts, cursor, N, E);
        fill_kernel<<<egrid, 512, 0, stream>>>(eidx, cursor, slotA, E);
        mlp_kernel<false, true, true><<<GRID, BLK, 0, stream>>>(
            x, xbf, nullptr, nullptr, nullptr, nw1, nb1, ng1, nbe1, nw2, nb2,
            hnb, nullptr, N, E);
        mlp_kernel<true, true, true><<<GRID, BLK, 0, stream>>>(
            x, xbf, ea, eidx, slotA, ew1, eb1, eg1, ebe1, ew2, eb2,
            h2, nullptr, N, E);
        upd3_kernel<true><<<ugrid, BLK, 0, stream>>>(
            hnb, h2, starts, x, xbf, uw, ub, lg, lb, (float*)d_out, N);
        return;
    }

    // Tier B layout (atomics, f32 agg)
    off = 0;
    unsigned short* hnb2 = (unsigned short*)alloc((size_t)N * D * 2);
    float* aggf = (float*)alloc((size_t)N * D * 4);
    unsigned short* xbf2 = (unsigned short*)alloc((size_t)N * D * 2);
    const size_t needB = off;

    hipMemsetAsync(aggf, 0, (size_t)N * D * 4, stream);
    if (ws_size >= needB) {
        cvt_count_kernel<<<(n8 + 511) / 512, 512, 0, stream>>>(
            x, xbf2, n8, nullptr, nullptr, 0);
        mlp_kernel<false, true, false><<<GRID, BLK, 0, stream>>>(
            x, xbf2, nullptr, nullptr, nullptr, nw1, nb1, ng1, nbe1, nw2, nb2,
            hnb2, nullptr, N, E);
        mlp_kernel<true, true, false><<<GRID, BLK, 0, stream>>>(
            x, xbf2, ea, eidx, nullptr, ew1, eb1, eg1, ebe1, ew2, eb2,
            nullptr, aggf, N, E);
        upd2_kernel<false, true><<<ugrid, BLK, 0, stream>>>(
            hnb2, aggf, x, xbf2, uw, ub, lg, lb, (float*)d_out, N);
    } else {
        mlp_kernel<false, false, false><<<GRID, BLK, 0, stream>>>(
            x, nullptr, nullptr, nullptr, nullptr, nw1, nb1, ng1, nbe1, nw2, nb2,
            hnb2, nullptr, N, E);
        mlp_kernel<true, false, false><<<GRID, BLK, 0, stream>>>(
            x, nullptr, ea, eidx, nullptr, ew1, eb1, eg1, ebe1, ew2, eb2,
            nullptr, aggf, N, E);
        upd2_kernel<false, false><<<ugrid, BLK, 0, stream>>>(
            hnb2, aggf, x, nullptr, uw, ub, lg, lb, (float*)d_out, N);
    }
}